// Round 5
// baseline (226.745 us; speedup 1.0000x reference)
//
#include <hip/hip_runtime.h>
#include <hip/hip_bf16.h>

#define IN_DIM    1024
#define HEAD_DIM  64
#define NUM_HEADS 16
#define SEQ       4096

// 1/sqrt(64) * log2(e), folded into Q (fp32, pre-bf16-cast). Softmax computed
// with exp2 (v_exp_f32 IS 2^x) -> no per-element ln2 prescale mul in attn.
#define QSCALE 0.18033688011112042f

typedef __bf16 bf16;
typedef __attribute__((ext_vector_type(4))) __bf16 bf16x4;
typedef __attribute__((ext_vector_type(8))) __bf16 bf16x8;
typedef __attribute__((ext_vector_type(4))) float floatx4;
typedef __attribute__((ext_vector_type(16))) float floatx16;
typedef __attribute__((ext_vector_type(4))) unsigned uint32x4;

__device__ __forceinline__ void async16(bf16* lds, const bf16* g) {
    __builtin_amdgcn_global_load_lds(
        (const __attribute__((address_space(1))) unsigned int*)g,
        (__attribute__((address_space(3))) unsigned int*)lds, 16, 0, 0);
}

__device__ __forceinline__ unsigned cvtpk_bf16(float lo, float hi) {
    unsigned r;
    asm("v_cvt_pk_bf16_f32 %0, %1, %2" : "=v"(r) : "v"(lo), "v"(hi));
    return r;
}

// v_permlane32_swap_b32 vdst, vsrc (CDNA4): vdst[32:63] <-> vsrc[0:31]
__device__ __forceinline__ void permswap(unsigned& a, unsigned& b) {
    asm("v_permlane32_swap_b32 %0, %1" : "+v"(a), "+v"(b));
}

// ---------------------------------------------------------------------------
// ws layout: hb @0 (8MB) | Wt @8MB (6MB) | Qb @14MB | Kb @22MB | Vt @30MB |
//            num @38MB (16MB f32) | denom @54MB (256KB f32)
// ---------------------------------------------------------------------------

__global__ void mha_zero(float4* __restrict__ p, int n4) {
    const float4 z = {0.f, 0.f, 0.f, 0.f};
    for (int i = blockIdx.x * blockDim.x + threadIdx.x; i < n4;
         i += gridDim.x * blockDim.x)
        p[i] = z;
}

__global__ void mha_conv_h(const float* __restrict__ h, bf16* __restrict__ hb) {
    int i = blockIdx.x * blockDim.x + threadIdx.x;
    float4 v = ((const float4*)h)[i];
    bf16x4 r;
    r[0] = (bf16)v.x; r[1] = (bf16)v.y; r[2] = (bf16)v.z; r[3] = (bf16)v.w;
    ((bf16x4*)hb)[i] = r;
}

__global__ void mha_conv_wt(const float* __restrict__ Wq, const float* __restrict__ Wk,
                            const float* __restrict__ Wv, bf16* __restrict__ Wt) {
    __shared__ bf16 tile[64][65];
    const int mat = blockIdx.z;
    const float* W = (mat == 0) ? Wq : (mat == 1) ? Wk : Wv;
    const int k0 = blockIdx.y * 64, n0 = blockIdx.x * 64;
    const int tn = threadIdx.x & 63, tq = threadIdx.x >> 6;
#pragma unroll
    for (int i = 0; i < 16; ++i) {
        int kk = tq + i * 4;
        tile[kk][tn] = (bf16)W[(size_t)(k0 + kk) * 1024 + n0 + tn];
    }
    __syncthreads();
#pragma unroll
    for (int i = 0; i < 16; ++i) {
        int nn = tq + i * 4;
        Wt[((size_t)mat << 20) + (size_t)(n0 + nn) * 1024 + k0 + tn] = tile[tn][nn];
    }
}

// ---------------------------------------------------------------------------
// QKV GEMM, m97-style: 128x128 tile, BK=32, global_load_lds staging,
// XOR-swizzled chunks so frag ds_read_b128 lands 2-way (free).  UNCHANGED.
// ---------------------------------------------------------------------------
__launch_bounds__(256)
__global__ void mha_qkv_gemm(const bf16* __restrict__ hb, const bf16* __restrict__ Wt,
                             const float* __restrict__ bq, const float* __restrict__ bk,
                             const float* __restrict__ bv,
                             bf16* __restrict__ Qb, bf16* __restrict__ Kb,
                             bf16* __restrict__ Vt) {
    __shared__ __align__(16) bf16 As[128 * 32];
    __shared__ __align__(16) bf16 Bs[128 * 32];

    const int lane = threadIdx.x & 63;
    const int wave = threadIdx.x >> 6;
    const int l16  = lane & 15;
    const int quad = lane >> 4;
    const int wm   = wave & 1;
    const int wn   = wave >> 1;

    const int m0  = blockIdx.x * 128;
    const int n0  = blockIdx.y * 128;
    const int mat = n0 >> 10;
    const int nc0 = n0 & 1023;

    const bf16* Wp = Wt + ((size_t)mat << 20);

    floatx4 acc[4][4] = {};
    const int swz = (l16 >> 1) & 3;

    for (int k0 = 0; k0 < IN_DIM; k0 += 32) {
#pragma unroll
        for (int r = 0; r < 2; ++r) {
            int g = wave * 128 + r * 64 + lane;
            int row = g >> 2, c = g & 3;
            int gc = c ^ ((row >> 1) & 3);
            bf16* ldsbase_a = As + (size_t)(wave * 128 + r * 64) * 8;
            bf16* ldsbase_b = Bs + (size_t)(wave * 128 + r * 64) * 8;
            async16(ldsbase_a, hb + (size_t)(m0 + row) * IN_DIM + k0 + gc * 8);
            async16(ldsbase_b, Wp + (size_t)(nc0 + row) * IN_DIM + k0 + gc * 8);
        }
        __syncthreads();

        bf16x8 af[4], bf[4];
#pragma unroll
        for (int mt = 0; mt < 4; ++mt)
            af[mt] = *(const bf16x8*)(As + (size_t)(wm * 64 + mt * 16 + l16) * 32
                                      + ((quad ^ swz) * 8));
#pragma unroll
        for (int nt = 0; nt < 4; ++nt)
            bf[nt] = *(const bf16x8*)(Bs + (size_t)(wn * 64 + nt * 16 + l16) * 32
                                      + ((quad ^ swz) * 8));
#pragma unroll
        for (int mt = 0; mt < 4; ++mt)
#pragma unroll
            for (int nt = 0; nt < 4; ++nt)
                acc[mt][nt] = __builtin_amdgcn_mfma_f32_16x16x32_bf16(af[mt], bf[nt],
                                                                      acc[mt][nt], 0, 0, 0);
        __syncthreads();
    }

    const float* bias = (mat == 0) ? bq : (mat == 1) ? bk : bv;
#pragma unroll
    for (int nt = 0; nt < 4; ++nt) {
        int nc = nc0 + wn * 64 + nt * 16 + l16;
        float bb = bias[nc];
        int head = nc >> 6, d = nc & 63;
#pragma unroll
        for (int mt = 0; mt < 4; ++mt)
#pragma unroll
            for (int r = 0; r < 4; ++r) {
                int srow = m0 + wm * 64 + mt * 16 + quad * 4 + r;
                float v = acc[mt][nt][r] + bb;
                if (mat == 0)
                    Qb[((size_t)head * SEQ + srow) * HEAD_DIM + d] = (bf16)(v * QSCALE);
                else if (mat == 1)
                    Kb[((size_t)head * SEQ + srow) * HEAD_DIM + d] = (bf16)v;
                else
                    Vt[((size_t)head * HEAD_DIM + d) * SEQ + srow] = (bf16)v;
            }
    }
}

// ---------------------------------------------------------------------------
// Attention v4: 2-way t-split for occupancy.  R4 post-mortem: counted-vmcnt +
// L2-resident K/V (FETCH 69.7->12.3MB) left time UNCHANGED (~99us) -> not
// memory-bound, not drain-bound; latency-bound at 2 waves/SIMD (no pipe
// >55%).  Fix: each (head, q-block) split into 2 blocks sweeping half the
// keys each -> 512 blocks = 2 independent blocks/CU x 8 waves = 16 waves/CU.
// No-max softmax makes partials combinable: blocks atomicAdd unnormalized
// O-numerator + rowsum; mha_norm divides afterwards.
// Iteration body byte-identical to verified R2/R4.  Wait ladder (2 DMA per
// tile per wave, NT=32): steady vmcnt(4); NT-2 -> vmcnt(2); NT-1 -> vmcnt(0).
// XCD map: head's both halves on same XCD (K/V + num stripes L2-local).
// ---------------------------------------------------------------------------
#define NT (SEQ / 64 / 2)   // 32 iters per block (half the keys)

__launch_bounds__(512)
__global__ void mha_attn(const bf16* __restrict__ Qb, const bf16* __restrict__ Kb,
                         const bf16* __restrict__ Vt, float* __restrict__ num,
                         float* __restrict__ denom) {
    __shared__ __align__(16) bf16 Ks[3][64 * 64];       // 24 KB
    __shared__ __align__(16) bf16 Vs[3][64 * 64];       // 24 KB (d-major V^T)

    const int lane = threadIdx.x & 63;
    const int wave = threadIdx.x >> 6;
    const int l31  = lane & 31;
    const int hi   = lane >> 5;

    // bid = (qx:4)(half:1)(hlsb:1)(xcd:3): XCD k owns heads {2k,2k+1}, both
    // halves -> per-XCD hot set = K/V 4MB + num stripe 2MB.
    const int bid  = blockIdx.x;
    const int xcd  = bid & 7;
    const int inner = bid >> 3;
    const int hh   = 2 * xcd + (inner & 1);
    const int half = (inner >> 1) & 1;
    const int qx   = inner >> 2;
    const int q0   = qx * 256 + wave * 32;
    const int tb   = half * (SEQ / 2);

    const bf16* Qh = Qb + (size_t)hh * SEQ * HEAD_DIM;
    const bf16* Kh = Kb + (size_t)hh * SEQ * HEAD_DIM;
    const bf16* Vh = Vt + (size_t)hh * HEAD_DIM * SEQ;

    // staging: 512 chunks of 16B per 64x64 tile; 512 threads stage 1 chunk
    // of K + 1 of V.  LDS[row][cc] <- G[row][cc ^ (row&7)] (source-swizzled,
    // dest linear as global_load_lds requires).
    const int sg   = wave * 64 + lane;           // 0..511
    const int srow = sg >> 3;                    // 0..63
    const int sgc  = (sg & 7) ^ (srow & 7);

    // Q fragments (B-operand of S^T): qf[ks][e] = Q[q0+l31][ks*16 + hi*8 + e]
    bf16x8 qf[4];
#pragma unroll
    for (int ks = 0; ks < 4; ++ks)
        qf[ks] = *(const bf16x8*)(Qh + (size_t)(q0 + l31) * HEAD_DIM + ks * 16 + hi * 8);

    bf16x8 vone;
#pragma unroll
    for (int i = 0; i < 8; ++i) vone[i] = (bf16)1.0f;

    floatx16 o0 = {}, o1 = {}, ol = {};
    const int swz = l31 & 7;

    // prologue: stage tiles 0,1; one-time full drain (also drains qf loads so
    // the in-loop counted vmcnt sees ONLY staging DMAs).
    async16(&Ks[0][wave * 512], Kh + (size_t)(tb + srow) * HEAD_DIM + sgc * 8);
    async16(&Vs[0][wave * 512], Vh + (size_t)srow * SEQ + tb + sgc * 8);
    async16(&Ks[1][wave * 512], Kh + (size_t)(tb + 64 + srow) * HEAD_DIM + sgc * 8);
    async16(&Vs[1][wave * 512], Vh + (size_t)srow * SEQ + tb + 64 + sgc * 8);
    asm volatile("s_waitcnt vmcnt(0)" ::: "memory");
    __builtin_amdgcn_s_barrier();

    int cur = 0;
    for (int t = 0; t < NT; ++t) {
        int pre = cur + 2; if (pre >= 3) pre -= 3;
        if (t + 2 < NT) {
            const int tg = tb + (t + 2) * 64;
            async16(&Ks[pre][wave * 512], Kh + (size_t)(tg + srow) * HEAD_DIM + sgc * 8);
            async16(&Vs[pre][wave * 512], Vh + (size_t)srow * SEQ + tg + sgc * 8);
        }
        if (t < NT - 2)       asm volatile("s_waitcnt vmcnt(4)" ::: "memory");
        else if (t == NT - 2) asm volatile("s_waitcnt vmcnt(2)" ::: "memory");
        else                  asm volatile("s_waitcnt vmcnt(0)" ::: "memory");
        __builtin_amdgcn_s_barrier();
        asm volatile("" ::: "memory");

        // ---- compute on buf[cur] (byte-identical to verified R2/R4 body) ----
        // K fragments: kf[tt][ks] = K[tt*32+l31][d = ks*16 + hi*8 ..+8]
        bf16x8 kf[2][4];
#pragma unroll
        for (int tt = 0; tt < 2; ++tt)
#pragma unroll
            for (int ks = 0; ks < 4; ++ks)
                kf[tt][ks] = *(const bf16x8*)(&Ks[cur][(tt * 32 + l31) * 64
                                              + (((ks * 2 + hi) ^ swz) * 8)]);

        // S^T tiles: rows t = (r&3)+8*(r>>2)+4*hi (+32*tt), col q = l31
        floatx16 s0 = {}, s1 = {};
#pragma unroll
        for (int ks = 0; ks < 4; ++ks)
            s0 = __builtin_amdgcn_mfma_f32_32x32x16_bf16(kf[0][ks], qf[ks], s0, 0, 0, 0);
#pragma unroll
        for (int ks = 0; ks < 4; ++ks)
            s1 = __builtin_amdgcn_mfma_f32_32x32x16_bf16(kf[1][ks], qf[ks], s1, 0, 0, 0);

        // V fragments: vf[dt][sl] = V[t = sl*16 + hi*8 ..+8][d = dt*32 + l31]
        bf16x8 vf[2][4];
#pragma unroll
        for (int dt = 0; dt < 2; ++dt)
#pragma unroll
            for (int sl = 0; sl < 4; ++sl)
                vf[dt][sl] = *(const bf16x8*)(&Vs[cur][(dt * 32 + l31) * 64
                                              + (((sl * 2 + hi) ^ swz) * 8)]);

        // p = exp2(s); pack PV A-frags in-register (cvt_pk + permlane32_swap;
        // swap is vdst.hi <-> vsrc.lo, arg order verified in R2).
        bf16x8 pa[4];
#pragma unroll
        for (int sl = 0; sl < 4; ++sl) {
            const floatx16 sv = (sl < 2) ? s0 : s1;
            const int rb = 8 * (sl & 1);
            float p0 = __builtin_amdgcn_exp2f(sv[rb + 0]);
            float p1 = __builtin_amdgcn_exp2f(sv[rb + 1]);
            float p2 = __builtin_amdgcn_exp2f(sv[rb + 2]);
            float p3 = __builtin_amdgcn_exp2f(sv[rb + 3]);
            float p4 = __builtin_amdgcn_exp2f(sv[rb + 4]);
            float p5 = __builtin_amdgcn_exp2f(sv[rb + 5]);
            float p6 = __builtin_amdgcn_exp2f(sv[rb + 6]);
            float p7 = __builtin_amdgcn_exp2f(sv[rb + 7]);
            unsigned u0 = cvtpk_bf16(p0, p1);
            unsigned u1 = cvtpk_bf16(p2, p3);
            unsigned u2 = cvtpk_bf16(p4, p5);
            unsigned u3 = cvtpk_bf16(p6, p7);
            permswap(u0, u2);
            permswap(u1, u3);
            uint32x4 w;
            w[0] = u0; w[1] = u1; w[2] = u2; w[3] = u3;
            pa[sl] = __builtin_bit_cast(bf16x8, w);
        }

        // O += P V ; ol += P 1   (ones-MFMA rowsum lands in O's layout)
#pragma unroll
        for (int sl = 0; sl < 4; ++sl) {
            o0 = __builtin_amdgcn_mfma_f32_32x32x16_bf16(pa[sl], vf[0][sl], o0, 0, 0, 0);
            o1 = __builtin_amdgcn_mfma_f32_32x32x16_bf16(pa[sl], vf[1][sl], o1, 0, 0, 0);
            ol = __builtin_amdgcn_mfma_f32_32x32x16_bf16(pa[sl], vone, ol, 0, 0, 0);
        }
        // ---- end compute ----

        asm volatile("" ::: "memory");
        __builtin_amdgcn_s_barrier();      // reads of buf[cur] done before restage
        cur = cur + 1; if (cur == 3) cur = 0;
    }

    // epilogue: accumulate UNNORMALIZED partials.  O rows q = q0 +
    // (r&3)+8*(r>>2)+4*hi, cols d = dt*32 + l31.  ol cols are identical
    // across l31 (every column of B=ones is the same) -> only l31==0 lanes
    // contribute the denominator.
#pragma unroll
    for (int r = 0; r < 16; ++r) {
        const int q = q0 + (r & 3) + 8 * (r >> 2) + 4 * hi;
        float* np = num + (size_t)q * (NUM_HEADS * HEAD_DIM) + hh * 64;
        atomicAdd(np + l31,      o0[r]);
        atomicAdd(np + 32 + l31, o1[r]);
        if (l31 == 0) atomicAdd(&denom[hh * SEQ + q], ol[r]);
    }
}

__global__ void mha_norm(const float* __restrict__ num, const float* __restrict__ denom,
                         float* __restrict__ out) {
    const int i = blockIdx.x * blockDim.x + threadIdx.x;   // float4 index
    const int flat = i * 4;
    const int q = flat >> 10;
    const int head = (flat & 1023) >> 6;
    float4 n = ((const float4*)num)[i];
    const float inv = 1.0f / denom[head * SEQ + q];
    n.x *= inv; n.y *= inv; n.z *= inv; n.w *= inv;
    ((float4*)out)[i] = n;
}

extern "C" void kernel_launch(void* const* d_in, const int* in_sizes, int n_in,
                              void* d_out, int out_size, void* d_ws, size_t ws_size,
                              hipStream_t stream) {
    const float* h  = (const float*)d_in[0];
    const float* Wq = (const float*)d_in[1];
    const float* Wk = (const float*)d_in[2];
    const float* Wv = (const float*)d_in[3];
    const float* bq = (const float*)d_in[4];
    const float* bk = (const float*)d_in[5];
    const float* bv = (const float*)d_in[6];
    float* out = (float*)d_out;

    char* ws = (char*)d_ws;
    const size_t MB = 1024 * 1024;
    bf16*  hb    = (bf16*)(ws);
    bf16*  Wt    = (bf16*)(ws + 8 * MB);
    bf16*  Qb    = (bf16*)(ws + 14 * MB);
    bf16*  Kb    = (bf16*)(ws + 22 * MB);
    bf16*  Vt    = (bf16*)(ws + 30 * MB);
    float* num   = (float*)(ws + 38 * MB);    // 16MB f32 [SEQ][1024]
    float* denom = (float*)(ws + 54 * MB);    // 256KB f32 [head][SEQ]

    // zero num+denom (contiguous 16.25MB)
    const int n4 = (16 * 1024 * 1024 + NUM_HEADS * SEQ * 4) / 16;
    mha_zero<<<2048, 256, 0, stream>>>((float4*)num, n4);
    mha_conv_h<<<(SEQ * IN_DIM / 4) / 256, 256, 0, stream>>>(h, hb);
    mha_conv_wt<<<dim3(16, 16, 3), 256, 0, stream>>>(Wq, Wk, Wv, Wt);
    mha_qkv_gemm<<<dim3(SEQ / 128, (3 * IN_DIM) / 128), 256, 0, stream>>>(
        hb, Wt, bq, bk, bv, Qb, Kb, Vt);
    // (qx:16) x (half:2) x (heads:16) = 512 blocks, 2 independent blocks/CU.
    mha_attn<<<dim3(512), 512, 0, stream>>>(Qb, Kb, Vt, num, denom);
    mha_norm<<<(SEQ * NUM_HEADS * HEAD_DIM / 4) / 256, 256, 0, stream>>>(num, denom, out);
}

// Round 6
// 211.815 us; speedup vs baseline: 1.0705x; 1.0705x over previous
//
#include <hip/hip_runtime.h>
#include <hip/hip_bf16.h>

#define IN_DIM    1024
#define HEAD_DIM  64
#define NUM_HEADS 16
#define SEQ       4096

// 1/sqrt(64) * log2(e), folded into Q (fp32, pre-bf16-cast). Softmax computed
// with exp2 (v_exp_f32 IS 2^x) -> no per-element ln2 prescale mul in attn.
#define QSCALE 0.18033688011112042f

typedef __bf16 bf16;
typedef __attribute__((ext_vector_type(4))) __bf16 bf16x4;
typedef __attribute__((ext_vector_type(8))) __bf16 bf16x8;
typedef __attribute__((ext_vector_type(4))) float floatx4;
typedef __attribute__((ext_vector_type(16))) float floatx16;
typedef __attribute__((ext_vector_type(4))) unsigned uint32x4;

__device__ __forceinline__ void async16(bf16* lds, const bf16* g) {
    __builtin_amdgcn_global_load_lds(
        (const __attribute__((address_space(1))) unsigned int*)g,
        (__attribute__((address_space(3))) unsigned int*)lds, 16, 0, 0);
}

__device__ __forceinline__ unsigned cvtpk_bf16(float lo, float hi) {
    unsigned r;
    asm("v_cvt_pk_bf16_f32 %0, %1, %2" : "=v"(r) : "v"(lo), "v"(hi));
    return r;
}

// v_permlane32_swap_b32 vdst, vsrc (CDNA4): vdst[32:63] <-> vsrc[0:31]
__device__ __forceinline__ void permswap(unsigned& a, unsigned& b) {
    asm("v_permlane32_swap_b32 %0, %1" : "+v"(a), "+v"(b));
}

// ---------------------------------------------------------------------------
// ws layout: hb @0 (8MB) | Wt @8MB (6MB, n-major) | Qb @14MB | Kb @22MB | Vt @30MB
// ---------------------------------------------------------------------------

__global__ void mha_conv_h(const float* __restrict__ h, bf16* __restrict__ hb) {
    int i = blockIdx.x * blockDim.x + threadIdx.x;
    float4 v = ((const float4*)h)[i];
    bf16x4 r;
    r[0] = (bf16)v.x; r[1] = (bf16)v.y; r[2] = (bf16)v.z; r[3] = (bf16)v.w;
    ((bf16x4*)hb)[i] = r;
}

__global__ void mha_conv_wt(const float* __restrict__ Wq, const float* __restrict__ Wk,
                            const float* __restrict__ Wv, bf16* __restrict__ Wt) {
    __shared__ bf16 tile[64][65];
    const int mat = blockIdx.z;
    const float* W = (mat == 0) ? Wq : (mat == 1) ? Wk : Wv;
    const int k0 = blockIdx.y * 64, n0 = blockIdx.x * 64;
    const int tn = threadIdx.x & 63, tq = threadIdx.x >> 6;
#pragma unroll
    for (int i = 0; i < 16; ++i) {
        int kk = tq + i * 4;
        tile[kk][tn] = (bf16)W[(size_t)(k0 + kk) * 1024 + n0 + tn];
    }
    __syncthreads();
#pragma unroll
    for (int i = 0; i < 16; ++i) {
        int nn = tq + i * 4;
        Wt[((size_t)mat << 20) + (size_t)(n0 + nn) * 1024 + k0 + tn] = tile[tn][nn];
    }
}

// ---------------------------------------------------------------------------
// QKV GEMM, m97-style main loop (128x128 tile, BK=32, global_load_lds
// staging, XOR-swizzled frag reads) -- UNCHANGED and verified.
// NEW (R6): LDS-staged coalesced epilogue.  The old epilogue did 64 scalar
// 2B stores/thread; for V^T they were stride-SEQ scattered (1 cacheline per
// store, ~16 L2 transactions per instr) -- theory: that scatter is why the
// GEMM ran ~90us instead of ~35.  Now each n-half (= one head) is staged in
// LDS (row-major [m][80] for Q/K, transposed [d][144] r-quad-packed for V),
// then stored as bf16x8 (16B/lane) fully-coalesced runs.
// ---------------------------------------------------------------------------
__launch_bounds__(256)
__global__ void mha_qkv_gemm(const bf16* __restrict__ hb, const bf16* __restrict__ Wt,
                             const float* __restrict__ bq, const float* __restrict__ bk,
                             const float* __restrict__ bv,
                             bf16* __restrict__ Qb, bf16* __restrict__ Kb,
                             bf16* __restrict__ Vt) {
    __shared__ __align__(16) bf16 As[128 * 32];
    __shared__ __align__(16) bf16 Bs[128 * 32];
    __shared__ __align__(16) bf16 es[128 * 80];    // 20KB epilogue staging

    const int lane = threadIdx.x & 63;
    const int wave = threadIdx.x >> 6;
    const int l16  = lane & 15;
    const int quad = lane >> 4;
    const int wm   = wave & 1;
    const int wn   = wave >> 1;

    const int m0  = blockIdx.x * 128;
    const int n0  = blockIdx.y * 128;
    const int mat = n0 >> 10;
    const int nc0 = n0 & 1023;

    const bf16* Wp = Wt + ((size_t)mat << 20);

    floatx4 acc[4][4] = {};
    const int swz = (l16 >> 1) & 3;

    for (int k0 = 0; k0 < IN_DIM; k0 += 32) {
#pragma unroll
        for (int r = 0; r < 2; ++r) {
            int g = wave * 128 + r * 64 + lane;
            int row = g >> 2, c = g & 3;
            int gc = c ^ ((row >> 1) & 3);
            bf16* ldsbase_a = As + (size_t)(wave * 128 + r * 64) * 8;
            bf16* ldsbase_b = Bs + (size_t)(wave * 128 + r * 64) * 8;
            async16(ldsbase_a, hb + (size_t)(m0 + row) * IN_DIM + k0 + gc * 8);
            async16(ldsbase_b, Wp + (size_t)(nc0 + row) * IN_DIM + k0 + gc * 8);
        }
        __syncthreads();

        bf16x8 af[4], bf[4];
#pragma unroll
        for (int mt = 0; mt < 4; ++mt)
            af[mt] = *(const bf16x8*)(As + (size_t)(wm * 64 + mt * 16 + l16) * 32
                                      + ((quad ^ swz) * 8));
#pragma unroll
        for (int nt = 0; nt < 4; ++nt)
            bf[nt] = *(const bf16x8*)(Bs + (size_t)(wn * 64 + nt * 16 + l16) * 32
                                      + ((quad ^ swz) * 8));
#pragma unroll
        for (int mt = 0; mt < 4; ++mt)
#pragma unroll
            for (int nt = 0; nt < 4; ++nt)
                acc[mt][nt] = __builtin_amdgcn_mfma_f32_16x16x32_bf16(af[mt], bf[nt],
                                                                      acc[mt][nt], 0, 0, 0);
        __syncthreads();
    }

    // ---- epilogue: bias (+QSCALE for Q) into acc, then staged stores ----
    const float* bias = (mat == 0) ? bq : (mat == 1) ? bk : bv;
#pragma unroll
    for (int nt = 0; nt < 4; ++nt) {
        float bb = bias[nc0 + wn * 64 + nt * 16 + l16];
#pragma unroll
        for (int mt = 0; mt < 4; ++mt)
#pragma unroll
            for (int r = 0; r < 4; ++r) {
                float v = acc[mt][nt][r] + bb;
                acc[mt][nt][r] = (mat == 0) ? v * QSCALE : v;
            }
    }

    const int tid = threadIdx.x;
#pragma unroll
    for (int h = 0; h < 2; ++h) {
        // write phase: waves with wn==h own this n-half (= head (nc0>>6)+h)
        if (wn == h) {
            if (mat < 2) {
                // es[m(128)][80]: row = local m, col = d
#pragma unroll
                for (int mt = 0; mt < 4; ++mt)
#pragma unroll
                    for (int nt = 0; nt < 4; ++nt)
#pragma unroll
                        for (int r = 0; r < 4; ++r)
                            es[(wm * 64 + mt * 16 + quad * 4 + r) * 80
                               + nt * 16 + l16] = (bf16)acc[mt][nt][r];
            } else {
                // es[d(64)][144]: row = d, col = local m; r-quad is m-contig
#pragma unroll
                for (int mt = 0; mt < 4; ++mt)
#pragma unroll
                    for (int nt = 0; nt < 4; ++nt) {
                        bf16x4 pk;
                        pk[0] = (bf16)acc[mt][nt][0];
                        pk[1] = (bf16)acc[mt][nt][1];
                        pk[2] = (bf16)acc[mt][nt][2];
                        pk[3] = (bf16)acc[mt][nt][3];
                        *(bf16x4*)&es[(nt * 16 + l16) * 144
                                      + wm * 64 + mt * 16 + quad * 4] = pk;
                    }
            }
        }
        __syncthreads();

        const int head = (nc0 >> 6) + h;
        if (mat < 2) {
            bf16* dst = (mat == 0 ? Qb : Kb) + ((size_t)head * SEQ + m0) * 64;
            // 128 rows x 64 d; 8 lanes x 16B per row, 32 rows per round
#pragma unroll
            for (int j = 0; j < 4; ++j) {
                int row = j * 32 + (tid >> 3);
                int col = (tid & 7) * 8;
                *(bf16x8*)&dst[(size_t)row * 64 + col]
                    = *(const bf16x8*)&es[row * 80 + col];
            }
        } else {
            // 64 d-rows x 128 m; 16 lanes x 16B per row, 16 rows per round
#pragma unroll
            for (int j = 0; j < 4; ++j) {
                int d = j * 16 + (tid >> 4);
                int col = (tid & 15) * 8;
                *(bf16x8*)&Vt[((size_t)(head * 64 + d)) * SEQ + m0 + col]
                    = *(const bf16x8*)&es[d * 144 + col];
            }
        }
        __syncthreads();   // es reused by next h
    }
}

// ---------------------------------------------------------------------------
// Attention (R4-exact, verified): 8 waves x 32 q-rows (256 q/block, 1
// block/CU), 32x32x16 MFMA, in-register P transpose, counted-vmcnt 3-buffer
// pipeline, XCD-head swizzle (K/V L2-resident, FETCH 69.7->12.3MB).
// R5 falsified both the drain theory (counted vmcnt: no change) and the
// occupancy theory (2x waves: no change) -> structure-bound ~99us; the
// t-split's atomics/zero/norm overhead (+20us) is reverted here.
// ---------------------------------------------------------------------------
__launch_bounds__(512)
__global__ void mha_attn(const bf16* __restrict__ Qb, const bf16* __restrict__ Kb,
                         const bf16* __restrict__ Vt, float* __restrict__ out) {
    __shared__ __align__(16) bf16 Ks[3][64 * 64];       // 24 KB
    __shared__ __align__(16) bf16 Vs[3][64 * 64];       // 24 KB (d-major V^T)

    const int lane = threadIdx.x & 63;
    const int wave = threadIdx.x >> 6;
    const int l31  = lane & 31;
    const int hi   = lane >> 5;

    // XCD-head swizzle: 256 blocks; XCD k (= bid%8) gets heads {2k, 2k+1}
    // -> per-XCD K/V working set = 4MB = its L2.
    const int bid = blockIdx.x;
    const int hh  = 2 * (bid & 7) + ((bid >> 3) & 1);
    const int qx  = bid >> 4;
    const int q0  = qx * 256 + wave * 32;

    const bf16* Qh = Qb + (size_t)hh * SEQ * HEAD_DIM;
    const bf16* Kh = Kb + (size_t)hh * SEQ * HEAD_DIM;
    const bf16* Vh = Vt + (size_t)hh * HEAD_DIM * SEQ;

    // staging: 512 chunks of 16B per 64x64 tile; 512 threads stage 1 chunk
    // of K + 1 of V.  LDS[row][cc] <- G[row][cc ^ (row&7)] (source-swizzled,
    // dest linear as global_load_lds requires).
    const int sg   = wave * 64 + lane;           // 0..511
    const int srow = sg >> 3;                    // 0..63
    const int sgc  = (sg & 7) ^ (srow & 7);

    // Q fragments (B-operand of S^T): qf[ks][e] = Q[q0+l31][ks*16 + hi*8 + e]
    bf16x8 qf[4];
#pragma unroll
    for (int ks = 0; ks < 4; ++ks)
        qf[ks] = *(const bf16x8*)(Qh + (size_t)(q0 + l31) * HEAD_DIM + ks * 16 + hi * 8);

    bf16x8 vone;
#pragma unroll
    for (int i = 0; i < 8; ++i) vone[i] = (bf16)1.0f;

    floatx16 o0 = {}, o1 = {}, ol = {};
    const int swz = l31 & 7;

    // prologue: stage tiles 0,1; one-time full drain (also drains qf loads so
    // the in-loop counted vmcnt sees ONLY staging DMAs).
    async16(&Ks[0][wave * 512], Kh + (size_t)srow * HEAD_DIM + sgc * 8);
    async16(&Vs[0][wave * 512], Vh + (size_t)srow * SEQ + 0 + sgc * 8);
    async16(&Ks[1][wave * 512], Kh + (size_t)(64 + srow) * HEAD_DIM + sgc * 8);
    async16(&Vs[1][wave * 512], Vh + (size_t)srow * SEQ + 64 + sgc * 8);
    asm volatile("s_waitcnt vmcnt(0)" ::: "memory");
    __builtin_amdgcn_s_barrier();

    int cur = 0;
    for (int t = 0; t < SEQ / 64; ++t) {
        int pre = cur + 2; if (pre >= 3) pre -= 3;
        if (t + 2 < SEQ / 64) {
            const int tg = (t + 2) * 64;
            async16(&Ks[pre][wave * 512], Kh + (size_t)(tg + srow) * HEAD_DIM + sgc * 8);
            async16(&Vs[pre][wave * 512], Vh + (size_t)srow * SEQ + tg + sgc * 8);
        }
        if (t < SEQ / 64 - 2)       asm volatile("s_waitcnt vmcnt(4)" ::: "memory");
        else if (t == SEQ / 64 - 2) asm volatile("s_waitcnt vmcnt(2)" ::: "memory");
        else                        asm volatile("s_waitcnt vmcnt(0)" ::: "memory");
        __builtin_amdgcn_s_barrier();
        asm volatile("" ::: "memory");

        // ---- compute on buf[cur] (byte-identical to verified R2/R4 body) ----
        bf16x8 kf[2][4];
#pragma unroll
        for (int tt = 0; tt < 2; ++tt)
#pragma unroll
            for (int ks = 0; ks < 4; ++ks)
                kf[tt][ks] = *(const bf16x8*)(&Ks[cur][(tt * 32 + l31) * 64
                                              + (((ks * 2 + hi) ^ swz) * 8)]);

        floatx16 s0 = {}, s1 = {};
#pragma unroll
        for (int ks = 0; ks < 4; ++ks)
            s0 = __builtin_amdgcn_mfma_f32_32x32x16_bf16(kf[0][ks], qf[ks], s0, 0, 0, 0);
#pragma unroll
        for (int ks = 0; ks < 4; ++ks)
            s1 = __builtin_amdgcn_mfma_f32_32x32x16_bf16(kf[1][ks], qf[ks], s1, 0, 0, 0);

        bf16x8 vf[2][4];
#pragma unroll
        for (int dt = 0; dt < 2; ++dt)
#pragma unroll
            for (int sl = 0; sl < 4; ++sl)
                vf[dt][sl] = *(const bf16x8*)(&Vs[cur][(dt * 32 + l31) * 64
                                              + (((sl * 2 + hi) ^ swz) * 8)]);

        bf16x8 pa[4];
#pragma unroll
        for (int sl = 0; sl < 4; ++sl) {
            const floatx16 sv = (sl < 2) ? s0 : s1;
            const int rb = 8 * (sl & 1);
            float p0 = __builtin_amdgcn_exp2f(sv[rb + 0]);
            float p1 = __builtin_amdgcn_exp2f(sv[rb + 1]);
            float p2 = __builtin_amdgcn_exp2f(sv[rb + 2]);
            float p3 = __builtin_amdgcn_exp2f(sv[rb + 3]);
            float p4 = __builtin_amdgcn_exp2f(sv[rb + 4]);
            float p5 = __builtin_amdgcn_exp2f(sv[rb + 5]);
            float p6 = __builtin_amdgcn_exp2f(sv[rb + 6]);
            float p7 = __builtin_amdgcn_exp2f(sv[rb + 7]);
            unsigned u0 = cvtpk_bf16(p0, p1);
            unsigned u1 = cvtpk_bf16(p2, p3);
            unsigned u2 = cvtpk_bf16(p4, p5);
            unsigned u3 = cvtpk_bf16(p6, p7);
            permswap(u0, u2);
            permswap(u1, u3);
            uint32x4 w;
            w[0] = u0; w[1] = u1; w[2] = u2; w[3] = u3;
            pa[sl] = __builtin_bit_cast(bf16x8, w);
        }

#pragma unroll
        for (int sl = 0; sl < 4; ++sl) {
            o0 = __builtin_amdgcn_mfma_f32_32x32x16_bf16(pa[sl], vf[0][sl], o0, 0, 0, 0);
            o1 = __builtin_amdgcn_mfma_f32_32x32x16_bf16(pa[sl], vf[1][sl], o1, 0, 0, 0);
            ol = __builtin_amdgcn_mfma_f32_32x32x16_bf16(pa[sl], vone, ol, 0, 0, 0);
        }
        // ---- end compute ----

        asm volatile("" ::: "memory");
        __builtin_amdgcn_s_barrier();      // reads of buf[cur] done before restage
        cur = cur + 1; if (cur == 3) cur = 0;
    }

    // epilogue: O rows q = q0 + (r&3)+8*(r>>2)+4*hi, cols d = dt*32 + l31
#pragma unroll
    for (int r = 0; r < 16; ++r) {
        const int q = q0 + (r & 3) + 8 * (r >> 2) + 4 * hi;
        const float inv = 1.0f / ol[r];
        out[(size_t)q * (NUM_HEADS * HEAD_DIM) + hh * 64 + l31]      = o0[r] * inv;
        out[(size_t)q * (NUM_HEADS * HEAD_DIM) + hh * 64 + 32 + l31] = o1[r] * inv;
    }
}

extern "C" void kernel_launch(void* const* d_in, const int* in_sizes, int n_in,
                              void* d_out, int out_size, void* d_ws, size_t ws_size,
                              hipStream_t stream) {
    const float* h  = (const float*)d_in[0];
    const float* Wq = (const float*)d_in[1];
    const float* Wk = (const float*)d_in[2];
    const float* Wv = (const float*)d_in[3];
    const float* bq = (const float*)d_in[4];
    const float* bk = (const float*)d_in[5];
    const float* bv = (const float*)d_in[6];
    float* out = (float*)d_out;

    char* ws = (char*)d_ws;
    const size_t MB = 1024 * 1024;
    bf16* hb = (bf16*)(ws);
    bf16* Wt = (bf16*)(ws + 8 * MB);
    bf16* Qb = (bf16*)(ws + 14 * MB);
    bf16* Kb = (bf16*)(ws + 22 * MB);
    bf16* Vt = (bf16*)(ws + 30 * MB);

    mha_conv_h<<<(SEQ * IN_DIM / 4) / 256, 256, 0, stream>>>(h, hb);
    mha_conv_wt<<<dim3(16, 16, 3), 256, 0, stream>>>(Wq, Wk, Wv, Wt);
    mha_qkv_gemm<<<dim3(SEQ / 128, (3 * IN_DIM) / 128), 256, 0, stream>>>(
        hb, Wt, bq, bk, bv, Qb, Kb, Vt);
    mha_attn<<<dim3((SEQ / 256) * NUM_HEADS), 512, 0, stream>>>(Qb, Kb, Vt, out);
}